// Round 6
// baseline (1940.071 us; speedup 1.0000x reference)
//
#include <hip/hip_runtime.h>

#define NN 50000
#define NE 800000
#define DD 128
#define NB 782          // buckets of 64 nodes
#define BSTRIDE 784
#define CHUNK 4096
#define BIN_BLOCKS ((NE + CHUNK - 1) / CHUNK)   // 196
#define H8SCALE 64.f
#define H8INV (1.f / 64.f)
#define HROWS (NN + 1)  // hp8 rows per conv; row NN is the all-zero row

typedef float floatx4 __attribute__((ext_vector_type(4)));
typedef float floatx2 __attribute__((ext_vector_type(2)));
typedef __bf16 bf16x8 __attribute__((ext_vector_type(8)));

__device__ __forceinline__ int clampn(int v) {
    return v < 0 ? 0 : (v >= NN ? NN - 1 : v);
}
__device__ __forceinline__ unsigned int f2bf(float f) {
    union { float f; unsigned int i; } v; v.f = f;
    unsigned int lsb = (v.i >> 16) & 1u;
    v.i += 0x7fffu + lsb;
    return (v.i >> 16) & 0xFFFFu;
}

// ---- W^T bf16 precompute + zero bHist/gpart (folds the memsets) ----
__global__ __launch_bounds__(256) void k_wt3(const float* __restrict__ w0,
                                             const float* __restrict__ w1,
                                             const float* __restrict__ w2,
                                             unsigned short* __restrict__ wtg,
                                             int* __restrict__ bHist,
                                             float* __restrict__ gpart) {
    int conv = blockIdx.x;
    const float* W = conv == 0 ? w0 : conv == 1 ? w1 : w2;
    unsigned short* o = wtg + conv * DD * DD;
    for (int i = threadIdx.x; i < BSTRIDE; i += 256) bHist[conv * BSTRIDE + i] = 0;
    for (int i = threadIdx.x; i < 4096; i += 256) gpart[conv * 4096 + i] = 0.f;
    for (int idx = threadIdx.x; idx < DD * DD; idx += 256) {
        int k = idx >> 7, c = idx & 127;
        o[c * DD + k] = (unsigned short)f2bf(W[idx]);
    }
}

// ---- pass 1: per-bucket edge counts ----
__global__ __launch_bounds__(256) void k_bcnt3(const int* __restrict__ e0,
                                               const int* __restrict__ e1,
                                               const int* __restrict__ e2,
                                               int* __restrict__ bHist) {
    __shared__ int hist[NB];
    const int* ei = (blockIdx.y == 0 ? e0 : blockIdx.y == 1 ? e1 : e2);
    int t = threadIdx.x;
    for (int b = t; b < NB; b += 256) hist[b] = 0;
    __syncthreads();
    int base = blockIdx.x * CHUNK;
    int chunk = NE - base; if (chunk > CHUNK) chunk = CHUNK;
    for (int i = t; i < chunk; i += 256) {
        int d = clampn(ei[NE + base + i]);
        atomicAdd(&hist[d >> 6], 1);
    }
    __syncthreads();
    for (int b = t; b < NB; b += 256)
        if (hist[b]) atomicAdd(&bHist[blockIdx.y * BSTRIDE + b], hist[b]);
}

// ---- pass 2: scan bucket counts -> bOff, bCur ----
__global__ __launch_bounds__(64) void k_bscan3(const int* __restrict__ bHist,
                                               int* __restrict__ bOff,
                                               int* __restrict__ bCur) {
    int conv = blockIdx.x;
    int lane = threadIdx.x;
    const int PER = (NB + 63) / 64;   // 13
    int basei = lane * PER;
    int loc[PER];
    int s = 0;
    for (int j = 0; j < PER; ++j) {
        int b = basei + j;
        int h = (b < NB) ? bHist[conv * BSTRIDE + b] : 0;
        loc[j] = h; s += h;
    }
    int incl = s;
    for (int off = 1; off < 64; off <<= 1) {
        int u = __shfl_up(incl, off);
        if (lane >= off) incl += u;
    }
    int run = incl - s;
    for (int j = 0; j < PER; ++j) {
        int b = basei + j;
        if (b < NB) {
            bOff[conv * BSTRIDE + b] = run;
            bCur[conv * BSTRIDE + b] = run;
            run += loc[j];
        }
    }
    if (lane == 63) bOff[conv * BSTRIDE + NB] = incl;
}

// ---- pass 3: block-local counting sort by bucket, coalesced flush ----
__global__ __launch_bounds__(256) void k_bin3(const int* __restrict__ e0,
                                              const int* __restrict__ e1,
                                              const int* __restrict__ e2,
                                              int* __restrict__ bCur,
                                              unsigned int* __restrict__ binned) {
    __shared__ int hist[NB];
    __shared__ int off[NB];
    __shared__ int delta[NB];
    __shared__ unsigned int stage[CHUNK];
    __shared__ unsigned short sbuck[CHUNK];
    const int* ei = (blockIdx.y == 0 ? e0 : blockIdx.y == 1 ? e1 : e2);
    int conv = blockIdx.y;
    int t = threadIdx.x;
    int base = blockIdx.x * CHUNK;
    int chunk = NE - base; if (chunk > CHUNK) chunk = CHUNK;

    for (int b = t; b < NB; b += 256) hist[b] = 0;
    __syncthreads();
    for (int i = t; i < chunk; i += 256) {
        int d = clampn(ei[NE + base + i]);
        atomicAdd(&hist[d >> 6], 1);
    }
    __syncthreads();
    if (t < 64) {
        const int PER = (NB + 63) / 64;
        int basei = t * PER;
        int loc[(NB + 63) / 64];
        int s = 0;
        for (int j = 0; j < PER; ++j) {
            int b = basei + j;
            int h = (b < NB) ? hist[b] : 0;
            loc[j] = h; s += h;
        }
        int incl = s;
        for (int o = 1; o < 64; o <<= 1) {
            int u = __shfl_up(incl, o);
            if (t >= o) incl += u;
        }
        int run = incl - s;
        for (int j = 0; j < PER; ++j) {
            int b = basei + j;
            if (b < NB) { off[b] = run; run += loc[j]; }
        }
    }
    __syncthreads();
    for (int b = t; b < NB; b += 256) {
        if (hist[b]) {
            int gp = atomicAdd(&bCur[conv * BSTRIDE + b], hist[b]);
            delta[b] = gp - off[b];
        }
    }
    __syncthreads();
    for (int i = t; i < chunk; i += 256) {
        int s = clampn(ei[base + i]);
        int d = clampn(ei[NE + base + i]);
        int b = d >> 6;
        int slot = atomicAdd(&off[b], 1);
        stage[slot] = (unsigned int)s | ((unsigned int)(d & 63) << 16);
        sbuck[slot] = (unsigned short)b;
    }
    __syncthreads();
    for (int i = t; i < chunk; i += 256)
        binned[(long)conv * NE + delta[sbuck[i]] + i] = stage[i];
}

// ---- MFMA gemm: h' = bf16(x)@bf16(W) * rsqrt(deg+1) * 64 -> fp8 ----
// per-node deg comes from histogramming this bucket's binned entries
// (bucket == 64-row gemm block). Also zeros row NN (gather padding target).
__global__ __launch_bounds__(256) void k_gemmb(
    const float* __restrict__ x0, const float* __restrict__ x1, const float* __restrict__ x2,
    const unsigned short* __restrict__ wtg,
    const unsigned int* __restrict__ binned, const int* __restrict__ bOff,
    unsigned char* __restrict__ hp8s, int n) {
    int conv = blockIdx.y;
    const float* x = conv == 0 ? x0 : conv == 1 ? x1 : x2;
    unsigned char* hp = hp8s + (size_t)conv * HROWS * DD;

    __shared__ __align__(16) unsigned short wt[128 * 136];  // W^T bf16, padded
    __shared__ __align__(16) unsigned short xb[64 * 136];   // x rows bf16, padded
    __shared__ int hist[64];
    int tid = threadIdx.x;
    int base = blockIdx.x * 64;

    if (tid < 64) hist[tid] = 0;
    __syncthreads();
    {
        int beg = bOff[conv * BSTRIDE + blockIdx.x];
        int end = bOff[conv * BSTRIDE + blockIdx.x + 1];
        for (int i = beg + tid; i < end; i += 256)
            atomicAdd(&hist[binned[(size_t)conv * NE + i] >> 16], 1);
    }

    if (blockIdx.x == 0 && tid < 32)
        reinterpret_cast<unsigned int*>(hp + (size_t)NN * DD)[tid] = 0u;

    const uint4* wg = reinterpret_cast<const uint4*>(wtg + conv * DD * DD);
#pragma unroll
    for (int it = 0; it < 8; ++it) {
        int chunk = it * 256 + tid;
        int c = chunk >> 4, gq = chunk & 15;
        *reinterpret_cast<uint4*>(&wt[c * 136 + gq * 8]) = wg[chunk];
    }
    const float4* x4p = reinterpret_cast<const float4*>(x);
#pragma unroll
    for (int it = 0; it < 8; ++it) {
        int idx = it * 256 + tid;
        int row = idx >> 5, c4 = idx & 31;
        int r = base + row;
        float4 v = (r < n) ? x4p[(long)r * 32 + c4] : float4{0.f, 0.f, 0.f, 0.f};
        unsigned int p0 = f2bf(v.x) | (f2bf(v.y) << 16);
        unsigned int p1 = f2bf(v.z) | (f2bf(v.w) << 16);
        uint2 pv = {p0, p1};
        *reinterpret_cast<uint2*>(&xb[row * 136 + c4 * 4]) = pv;
    }
    __syncthreads();

    int wave = tid >> 6, lane = tid & 63;
    int quad = lane >> 4, m = lane & 15;
    int rowb = wave * 16;

    bf16x8 a[4];
#pragma unroll
    for (int s = 0; s < 4; ++s)
        a[s] = *reinterpret_cast<const bf16x8*>(&xb[(rowb + m) * 136 + s * 32 + quad * 8]);

    floatx4 acc[8] = {};
#pragma unroll
    for (int j = 0; j < 8; ++j) {
#pragma unroll
        for (int s = 0; s < 4; ++s) {
            bf16x8 b = *reinterpret_cast<const bf16x8*>(&wt[(j * 16 + m) * 136 + s * 32 + quad * 8]);
            acc[j] = __builtin_amdgcn_mfma_f32_16x16x32_bf16(a[s], b, acc[j], 0, 0, 0);
        }
    }
#pragma unroll
    for (int r = 0; r < 4; ++r) {
        int rr = base + rowb + quad * 4 + r;
        if (rr < n) {
            float dvs = rsqrtf((float)(hist[rowb + quad * 4 + r] + 1)) * H8SCALE;
            unsigned char* rowp = hp + (long)rr * DD;
#pragma unroll
            for (int j = 0; j < 8; ++j) {
                float v = acc[j][r] * dvs;
                int p = __builtin_amdgcn_cvt_pk_fp8_f32(v, v, 0, false);
                rowp[j * 16 + m] = (unsigned char)(p & 0xFF);
            }
        }
    }
}

// ---- fused sort+gather: per bucket, accumulate source rows into LDS fp32
// acc[64][132] via ds_add_f32 directly from bucket-grouped binned entries.
// Replaces k_sort3 + CSR gather: no adj/rowptr/deg arrays, one less edge pass.
// Epilogue: self + norm + bias + relu + pool partial -> 32-shard atomic. ----
__global__ __launch_bounds__(256) void k_gacc(const unsigned char* __restrict__ hp8s,
                                              const unsigned int* __restrict__ binned,
                                              const int* __restrict__ bOff,
                                              const float* __restrict__ cb0,
                                              const float* __restrict__ cb1,
                                              const float* __restrict__ cb2,
                                              float* __restrict__ gpart) {
    __shared__ float acc[64][132];
    __shared__ unsigned int ent[2056];
    __shared__ int hist[64];
    __shared__ float bls[128];
    __shared__ float tmp[128];
    int b = blockIdx.x, conv = blockIdx.y;
    int tid = threadIdx.x;
    const unsigned char* hpb = hp8s + (size_t)conv * HROWS * DD;
    const float* bias = conv == 0 ? cb0 : conv == 1 ? cb1 : cb2;

    for (int i = tid; i < 64 * 132; i += 256) (&acc[0][0])[i] = 0.f;
    if (tid < 64) hist[tid] = 0;
    if (tid < 128) bls[tid] = bias[tid];
    __syncthreads();

    int beg = bOff[conv * BSTRIDE + b], end = bOff[conv * BSTRIDE + b + 1];
    int lane = tid & 63, wv = tid >> 6, l5 = lane & 31, half = lane >> 5;

    for (int cb = beg; cb < end; cb += 2048) {
        int cnum = end - cb; if (cnum > 2048) cnum = 2048;
        for (int i = tid; i < cnum; i += 256) {
            unsigned e = binned[(size_t)conv * NE + cb + i];
            ent[i] = e;
            atomicAdd(&hist[e >> 16], 1);
        }
        if (tid < 8) ent[cnum + tid] = 0u;   // pad (masked below)
        __syncthreads();
        for (int i = wv * 8; i < cnum; i += 32) {
            int dlv[4]; bool ok[4]; unsigned uv[4];
#pragma unroll
            for (int j = 0; j < 4; ++j) {
                int ia = i + 2 * j + half;        // <= i+7 <= cnum+6 (padded)
                unsigned e = ent[ia];
                ok[j] = ia < cnum;
                int src = (int)(e & 0xFFFFu);
                dlv[j] = (int)(e >> 16);
                uv[j] = *reinterpret_cast<const unsigned*>(
                    hpb + (((unsigned)src << 7) | ((unsigned)l5 << 2)));
            }
#pragma unroll
            for (int j = 0; j < 4; ++j) {
                unsigned u = ok[j] ? uv[j] : 0u;
                floatx2 f0 = __builtin_amdgcn_cvt_pk_f32_fp8((int)u, false);
                floatx2 f1 = __builtin_amdgcn_cvt_pk_f32_fp8((int)u, true);
                float* ap = &acc[dlv[j]][l5 * 4];
                atomicAdd(ap + 0, f0.x);
                atomicAdd(ap + 1, f0.y);
                atomicAdd(ap + 2, f1.x);
                atomicAdd(ap + 3, f1.y);
            }
        }
        __syncthreads();
    }

    // epilogue: thread -> channel c = tid&127, dst half dh = tid>>7 (32 dsts)
    int c = tid & 127, dh = tid >> 7;
    float psum = 0.f;
    int base = b * 64;
    for (int dd = 0; dd < 32; ++dd) {
        int d = dh * 32 + dd;
        int v = base + d;
        if (v >= NN) break;
        unsigned sw = *reinterpret_cast<const unsigned*>(
            hpb + (((unsigned)v << 7) | (unsigned)(c & ~3)));
        floatx2 sp0 = __builtin_amdgcn_cvt_pk_f32_fp8((int)sw, false);
        floatx2 sp1 = __builtin_amdgcn_cvt_pk_f32_fp8((int)sw, true);
        float sfl = (c & 2) ? sp1.x : sp0.x;
        float sfh = (c & 2) ? sp1.y : sp0.y;
        float sf = (c & 1) ? sfh : sfl;
        float dv = rsqrtf((float)(hist[d] + 1)) * H8INV;
        psum += fmaxf(dv * (acc[d][c] + sf) + bls[c], 0.f);
    }
    if (dh == 1) tmp[c] = psum;
    __syncthreads();
    if (dh == 0) {
        psum += tmp[c];
        unsafeAtomicAdd(&gpart[(size_t)(b & 31) * 384 + conv * DD + c], psum);
    }
}

// ---- head MLP: 256 threads, float4 weight reads, split-j reduction ----
__global__ __launch_bounds__(256) void k_head(const float* __restrict__ gpart,
    const float* __restrict__ w1, const float* __restrict__ b1,
    const float* __restrict__ w2, const float* __restrict__ b2,
    const float* __restrict__ w3, const float* __restrict__ b3,
    const float* __restrict__ f1w, const float* __restrict__ f1b,
    const float* __restrict__ f2w, const float* __restrict__ f2b,
    float* __restrict__ out) {
    __shared__ float xin[384], part[256], h1[128], h2[128], aw[3], xctx[128];
    int t = threadIdx.x;
    int o = t & 127, half = t >> 7;
    for (int i = t; i < 384; i += 256) {
        float s = 0.f;
        for (int sh = 0; sh < 32; ++sh) s += gpart[sh * 384 + i];
        xin[i] = s;
    }
    __syncthreads();
    {
        const float4* wrow = reinterpret_cast<const float4*>(w1 + o * 384 + half * 192);
        const float* xi = xin + half * 192;
        float s = 0.f;
#pragma unroll
        for (int j4 = 0; j4 < 48; ++j4) {
            float4 w = wrow[j4];
            s += w.x * xi[j4 * 4] + w.y * xi[j4 * 4 + 1] + w.z * xi[j4 * 4 + 2] + w.w * xi[j4 * 4 + 3];
        }
        part[t] = s;
    }
    __syncthreads();
    if (t < 128) h1[t] = fmaxf(part[t] + part[t + 128] + b1[t], 0.f);
    __syncthreads();
    {
        const float4* wrow = reinterpret_cast<const float4*>(w2 + o * 128 + half * 64);
        const float* xi = h1 + half * 64;
        float s = 0.f;
#pragma unroll
        for (int j4 = 0; j4 < 16; ++j4) {
            float4 w = wrow[j4];
            s += w.x * xi[j4 * 4] + w.y * xi[j4 * 4 + 1] + w.z * xi[j4 * 4 + 2] + w.w * xi[j4 * 4 + 3];
        }
        part[t] = s;
    }
    __syncthreads();
    if (t < 128) h2[t] = fmaxf(part[t] + part[t + 128] + b2[t], 0.f);
    __syncthreads();
    if (t < 3) {
        float sl = b3[t];
        for (int j = 0; j < 128; ++j) sl += h2[j] * w3[t * 128 + j];
        aw[t] = sl;
    }
    __syncthreads();
    if (t == 0) {
        float mx = fmaxf(aw[0], fmaxf(aw[1], aw[2]));
        float e0 = expf(aw[0] - mx), e1 = expf(aw[1] - mx), e2 = expf(aw[2] - mx);
        float inv = 1.f / (e0 + e1 + e2);
        aw[0] = e0 * inv; aw[1] = e1 * inv; aw[2] = e2 * inv;
    }
    __syncthreads();
    if (t < 128) xctx[t] = aw[0] * xin[t] + aw[1] * xin[128 + t] + aw[2] * xin[256 + t];
    __syncthreads();
    {
        const float* fw = half ? f2w : f1w;
        const float* fb = half ? f2b : f1b;
        const float4* wrow = reinterpret_cast<const float4*>(fw + o * 128);
        float s = fb[o];
#pragma unroll
        for (int j4 = 0; j4 < 32; ++j4) {
            float4 w = wrow[j4];
            s += w.x * xctx[j4 * 4] + w.y * xctx[j4 * 4 + 1] + w.z * xctx[j4 * 4 + 2] + w.w * xctx[j4 * 4 + 3];
        }
        out[half * 128 + o] = tanhf(s);
    }
}

extern "C" void kernel_launch(void* const* d_in, const int* in_sizes, int n_in,
                              void* d_out, int out_size, void* d_ws, size_t ws_size,
                              hipStream_t stream) {
    (void)in_sizes; (void)n_in; (void)out_size; (void)ws_size;

    const float* x[3]  = {(const float*)d_in[0], (const float*)d_in[1], (const float*)d_in[2]};
    const int*   ei[3] = {(const int*)d_in[3], (const int*)d_in[4], (const int*)d_in[5]};
    const float* cw[3] = {(const float*)d_in[6], (const float*)d_in[8], (const float*)d_in[10]};
    const float* cb[3] = {(const float*)d_in[7], (const float*)d_in[9], (const float*)d_in[11]};

    // layout: binned and hp8 both live (no overlay needed anymore)
    char* ws = (char*)d_ws;
    unsigned int*   binned = (unsigned int*)ws;                //  9,600,000
    int*            bHist  = (int*)(ws + 9600000);             //      9,408
    int*            bOff   = (int*)(ws + 9609408);             //      9,408
    int*            bCur   = (int*)(ws + 9618816);             //      9,408
    float*          gpart  = (float*)(ws + 9628224);           //     49,152 (32 shards x 384)
    unsigned short* wtg    = (unsigned short*)(ws + 9677376);  //     98,304
    unsigned char*  hp8    = (unsigned char*)(ws + 9775680);   // 19,200,384 (3 x (NN+1) x 128)

    dim3 bin_grid(BIN_BLOCKS, 3);
    k_wt3   <<<3, 256, 0, stream>>>(cw[0], cw[1], cw[2], wtg, bHist, gpart);
    k_bcnt3 <<<bin_grid, 256, 0, stream>>>(ei[0], ei[1], ei[2], bHist);
    k_bscan3<<<3, 64, 0, stream>>>(bHist, bOff, bCur);
    k_bin3  <<<bin_grid, 256, 0, stream>>>(ei[0], ei[1], ei[2], bCur, binned);

    k_gemmb<<<dim3(NB, 3), 256, 0, stream>>>(x[0], x[1], x[2], wtg, binned, bOff, hp8, NN);
    k_gacc <<<dim3(NB, 3), 256, 0, stream>>>(hp8, binned, bOff, cb[0], cb[1], cb[2], gpart);

    k_head<<<1, 256, 0, stream>>>(gpart,
        (const float*)d_in[12], (const float*)d_in[13],
        (const float*)d_in[14], (const float*)d_in[15],
        (const float*)d_in[16], (const float*)d_in[17],
        (const float*)d_in[18], (const float*)d_in[19],
        (const float*)d_in[20], (const float*)d_in[21],
        (float*)d_out);
}

// Round 7
// 366.626 us; speedup vs baseline: 5.2917x; 5.2917x over previous
//
#include <hip/hip_runtime.h>

#define NN 50000
#define NE 800000
#define DD 128
#define NB 782          // buckets of 64 nodes
#define BSTRIDE 784
#define RPS 50016       // rowptr per-conv stride
#define CHUNK 4096
#define BIN_BLOCKS ((NE + CHUNK - 1) / CHUNK)   // 196
#define H4SCALE 192.f
#define H4INV (1.f / 192.f)
#define HROWS (NN + 1)  // int4 rows per conv; row NN is the all-zero (nibble 8) row
#define NPAIR (NN / 2)

typedef float floatx4 __attribute__((ext_vector_type(4)));
typedef float floatx2 __attribute__((ext_vector_type(2)));
typedef __bf16 bf16x8 __attribute__((ext_vector_type(8)));

__device__ __forceinline__ int clampn(int v) {
    return v < 0 ? 0 : (v >= NN ? NN - 1 : v);
}
__device__ __forceinline__ unsigned int f2bf(float f) {
    union { float f; unsigned int i; } v; v.f = f;
    unsigned int lsb = (v.i >> 16) & 1u;
    v.i += 0x7fffu + lsb;
    return (v.i >> 16) & 0xFFFFu;
}

// ---- W^T bf16 precompute + zero bHist/g (folds the memsets) ----
__global__ __launch_bounds__(256) void k_wt3(const float* __restrict__ w0,
                                             const float* __restrict__ w1,
                                             const float* __restrict__ w2,
                                             unsigned short* __restrict__ wtg,
                                             int* __restrict__ bHist,
                                             float* __restrict__ g) {
    int conv = blockIdx.x;
    const float* W = conv == 0 ? w0 : conv == 1 ? w1 : w2;
    unsigned short* o = wtg + conv * DD * DD;
    for (int i = threadIdx.x; i < BSTRIDE; i += 256) bHist[conv * BSTRIDE + i] = 0;
    for (int i = threadIdx.x; i < DD; i += 256) g[conv * DD + i] = 0.f;
    for (int idx = threadIdx.x; idx < DD * DD; idx += 256) {
        int k = idx >> 7, c = idx & 127;
        o[c * DD + k] = (unsigned short)f2bf(W[idx]);
    }
}

// ---- pass 1: per-bucket edge counts ----
__global__ __launch_bounds__(256) void k_bcnt3(const int* __restrict__ e0,
                                               const int* __restrict__ e1,
                                               const int* __restrict__ e2,
                                               int* __restrict__ bHist) {
    __shared__ int hist[NB];
    const int* ei = (blockIdx.y == 0 ? e0 : blockIdx.y == 1 ? e1 : e2);
    int t = threadIdx.x;
    for (int b = t; b < NB; b += 256) hist[b] = 0;
    __syncthreads();
    int base = blockIdx.x * CHUNK;
    int chunk = NE - base; if (chunk > CHUNK) chunk = CHUNK;
    for (int i = t; i < chunk; i += 256) {
        int d = clampn(ei[NE + base + i]);
        atomicAdd(&hist[d >> 6], 1);
    }
    __syncthreads();
    for (int b = t; b < NB; b += 256)
        if (hist[b]) atomicAdd(&bHist[blockIdx.y * BSTRIDE + b], hist[b]);
}

// ---- pass 2: scan bucket counts -> bOff, bCur ----
__global__ __launch_bounds__(64) void k_bscan3(const int* __restrict__ bHist,
                                               int* __restrict__ bOff,
                                               int* __restrict__ bCur) {
    int conv = blockIdx.x;
    int lane = threadIdx.x;
    const int PER = (NB + 63) / 64;   // 13
    int basei = lane * PER;
    int loc[PER];
    int s = 0;
    for (int j = 0; j < PER; ++j) {
        int b = basei + j;
        int h = (b < NB) ? bHist[conv * BSTRIDE + b] : 0;
        loc[j] = h; s += h;
    }
    int incl = s;
    for (int off = 1; off < 64; off <<= 1) {
        int u = __shfl_up(incl, off);
        if (lane >= off) incl += u;
    }
    int run = incl - s;
    for (int j = 0; j < PER; ++j) {
        int b = basei + j;
        if (b < NB) {
            bOff[conv * BSTRIDE + b] = run;
            bCur[conv * BSTRIDE + b] = run;
            run += loc[j];
        }
    }
    if (lane == 63) bOff[conv * BSTRIDE + NB] = incl;
}

// ---- pass 3: block-local counting sort by bucket, coalesced flush ----
__global__ __launch_bounds__(256) void k_bin3(const int* __restrict__ e0,
                                              const int* __restrict__ e1,
                                              const int* __restrict__ e2,
                                              int* __restrict__ bCur,
                                              unsigned int* __restrict__ binned) {
    __shared__ int hist[NB];
    __shared__ int off[NB];
    __shared__ int delta[NB];
    __shared__ unsigned int stage[CHUNK];
    __shared__ unsigned short sbuck[CHUNK];
    const int* ei = (blockIdx.y == 0 ? e0 : blockIdx.y == 1 ? e1 : e2);
    int conv = blockIdx.y;
    int t = threadIdx.x;
    int base = blockIdx.x * CHUNK;
    int chunk = NE - base; if (chunk > CHUNK) chunk = CHUNK;

    for (int b = t; b < NB; b += 256) hist[b] = 0;
    __syncthreads();
    for (int i = t; i < chunk; i += 256) {
        int d = clampn(ei[NE + base + i]);
        atomicAdd(&hist[d >> 6], 1);
    }
    __syncthreads();
    if (t < 64) {
        const int PER = (NB + 63) / 64;
        int basei = t * PER;
        int loc[(NB + 63) / 64];
        int s = 0;
        for (int j = 0; j < PER; ++j) {
            int b = basei + j;
            int h = (b < NB) ? hist[b] : 0;
            loc[j] = h; s += h;
        }
        int incl = s;
        for (int o = 1; o < 64; o <<= 1) {
            int u = __shfl_up(incl, o);
            if (t >= o) incl += u;
        }
        int run = incl - s;
        for (int j = 0; j < PER; ++j) {
            int b = basei + j;
            if (b < NB) { off[b] = run; run += loc[j]; }
        }
    }
    __syncthreads();
    for (int b = t; b < NB; b += 256) {
        if (hist[b]) {
            int gp = atomicAdd(&bCur[conv * BSTRIDE + b], hist[b]);
            delta[b] = gp - off[b];
        }
    }
    __syncthreads();
    for (int i = t; i < chunk; i += 256) {
        int s = clampn(ei[base + i]);
        int d = clampn(ei[NE + base + i]);
        int b = d >> 6;
        int slot = atomicAdd(&off[b], 1);
        stage[slot] = (unsigned int)s | ((unsigned int)(d & 63) << 16);
        sbuck[slot] = (unsigned short)b;
    }
    __syncthreads();
    for (int i = t; i < chunk; i += 256)
        binned[(long)conv * NE + delta[sbuck[i]] + i] = stage[i];
}

// ---- pass 4: within-bucket sort by node -> adj, deg, rowptr ----
__global__ __launch_bounds__(256) void k_sort3(const unsigned int* __restrict__ binned,
                                               const int* __restrict__ bOff,
                                               int* __restrict__ adj,
                                               int* __restrict__ deg,
                                               int* __restrict__ rowptr) {
    __shared__ int cnt[64];
    __shared__ int cur[64];
    int b = blockIdx.x, conv = blockIdx.y;
    int t = threadIdx.x;
    int beg = bOff[conv * BSTRIDE + b], end = bOff[conv * BSTRIDE + b + 1];
    const unsigned int* bp = binned + (long)conv * NE;
    if (t < 64) cnt[t] = 0;
    __syncthreads();
    for (int i = beg + t; i < end; i += 256)
        atomicAdd(&cnt[(bp[i] >> 16) & 63], 1);
    __syncthreads();
    if (t < 64) {
        int c = cnt[t];
        int incl = c;
        for (int o = 1; o < 64; o <<= 1) {
            int u = __shfl_up(incl, o);
            if (t >= o) incl += u;
        }
        cur[t] = beg + incl - c;
        int v = b * 64 + t;
        if (v < NN) {
            deg[conv * NN + v] = c;
            rowptr[conv * RPS + v] = beg + incl - c;
            if (v == NN - 1) rowptr[conv * RPS + NN] = beg + incl;
        }
    }
    __syncthreads();
    for (int i = beg + t; i < end; i += 256) {
        unsigned int e = bp[i];
        int dl = (e >> 16) & 63;
        int pos = atomicAdd(&cur[dl], 1);
        adj[(long)conv * NE + pos] = (int)(e & 0xFFFFu);
    }
}

// ---- batched MFMA gemm: q = clamp(round(bf16(x)@bf16(W) * rsqrt(deg+1) * 192), -8, 7)
// packed int4 rows (64B: lane m owns bytes [4m,4m+4), nibble j = channel j*16+m).
// Row NN = all nibbles 8 (encodes 0) -> gather padding target. ----
__global__ __launch_bounds__(256) void k_gemmb(
    const float* __restrict__ x0, const float* __restrict__ x1, const float* __restrict__ x2,
    const unsigned short* __restrict__ wtg,
    const int* __restrict__ deg, unsigned char* __restrict__ hp4s, int n) {
    int conv = blockIdx.y;
    const float* x = conv == 0 ? x0 : conv == 1 ? x1 : x2;
    const int* dg = deg + conv * NN;
    unsigned char* hp = hp4s + (size_t)conv * HROWS * 64;

    __shared__ __align__(16) unsigned short wt[128 * 136];  // W^T bf16, padded
    __shared__ __align__(16) unsigned short xb[64 * 136];   // x rows bf16, padded
    int tid = threadIdx.x;
    int base = blockIdx.x * 64;

    if (blockIdx.x == 0 && tid < 16)
        reinterpret_cast<unsigned int*>(hp + (size_t)NN * 64)[tid] = 0x88888888u;

    const uint4* wg = reinterpret_cast<const uint4*>(wtg + conv * DD * DD);
#pragma unroll
    for (int it = 0; it < 8; ++it) {
        int chunk = it * 256 + tid;
        int c = chunk >> 4, gq = chunk & 15;
        *reinterpret_cast<uint4*>(&wt[c * 136 + gq * 8]) = wg[chunk];
    }
    const float4* x4p = reinterpret_cast<const float4*>(x);
#pragma unroll
    for (int it = 0; it < 8; ++it) {
        int idx = it * 256 + tid;
        int row = idx >> 5, c4 = idx & 31;
        int r = base + row;
        float4 v = (r < n) ? x4p[(long)r * 32 + c4] : float4{0.f, 0.f, 0.f, 0.f};
        unsigned int p0 = f2bf(v.x) | (f2bf(v.y) << 16);
        unsigned int p1 = f2bf(v.z) | (f2bf(v.w) << 16);
        uint2 pv = {p0, p1};
        *reinterpret_cast<uint2*>(&xb[row * 136 + c4 * 4]) = pv;
    }
    __syncthreads();

    int wave = tid >> 6, lane = tid & 63;
    int quad = lane >> 4, m = lane & 15;
    int rowb = wave * 16;

    bf16x8 a[4];
#pragma unroll
    for (int s = 0; s < 4; ++s)
        a[s] = *reinterpret_cast<const bf16x8*>(&xb[(rowb + m) * 136 + s * 32 + quad * 8]);

    floatx4 acc[8] = {};
#pragma unroll
    for (int j = 0; j < 8; ++j) {
#pragma unroll
        for (int s = 0; s < 4; ++s) {
            bf16x8 b = *reinterpret_cast<const bf16x8*>(&wt[(j * 16 + m) * 136 + s * 32 + quad * 8]);
            acc[j] = __builtin_amdgcn_mfma_f32_16x16x32_bf16(a[s], b, acc[j], 0, 0, 0);
        }
    }
#pragma unroll
    for (int r = 0; r < 4; ++r) {
        int rr = base + rowb + quad * 4 + r;
        if (rr < n) {
            float dvs = rsqrtf((float)(dg[rr] + 1)) * H4SCALE;
            unsigned pack = 0u;
#pragma unroll
            for (int j = 0; j < 8; ++j) {
                float v = acc[j][r] * dvs;
                int q = (int)lrintf(v);
                q = q < -8 ? -8 : (q > 7 ? 7 : q);
                pack |= (unsigned)(q + 8) << (4 * j);
            }
            *reinterpret_cast<unsigned*>(hp + (size_t)rr * 64 + m * 4) = pack;
        }
    }
}

// ---- int4 gather: wave = node pair (half 0/1), 4 groups of 16 lanes.
// Group (h,e): node h, edge parity e. 16 lanes x dword cover one 64B row
// => 4 rows per load instr, 1 sector-request per edge (the R2 wall halved).
// Nibbles accumulate packed (byte-SIMD adds, flush every window); pad slots
// read the hot nibble-8 row NN; bias 8/slot removed analytically. ----
#define KS(K) { int sl_ = __builtin_amdgcn_ds_bpermute(bpb + ((K) << 3), ent);          \
    unsigned u_ = *reinterpret_cast<const unsigned*>(hpb + (((unsigned)sl_ << 6) | ch4)); \
    aacc += u_ & 0x0F0F0F0Fu; bacc += (u_ >> 4) & 0x0F0F0F0Fu; }

__global__ __launch_bounds__(256) void k_gath4(const unsigned char* __restrict__ hp4s,
                                               const int* __restrict__ rowptr,
                                               const int* __restrict__ adj,
                                               const float* __restrict__ cb0,
                                               const float* __restrict__ cb1,
                                               const float* __restrict__ cb2,
                                               float* __restrict__ gout) {
    int conv = blockIdx.y;
    const unsigned char* hpb = hp4s + (size_t)conv * HROWS * 64;
    const int* rp = rowptr + conv * RPS;
    const int* ad = adj + (long)conv * NE;
    const float* bias = conv == 0 ? cb0 : conv == 1 ? cb1 : cb2;
    float* go = gout + conv * DD;

    int tid = threadIdx.x;
    int lane = tid & 63, wv = tid >> 6;
    int half = lane >> 5;                 // node within pair
    int il = lane & 31;                   // edge staging slot within half
    int l4 = lane & 15;                   // channel group
    unsigned ch4 = (unsigned)(l4 << 2);
    int bpb = ((lane & 32) << 2) | ((lane & 16) >> 2);
    int egrp = (lane >> 4) & 1;

    float bj0 = bias[0 * 16 + l4], bj1 = bias[1 * 16 + l4];
    float bj2 = bias[2 * 16 + l4], bj3 = bias[3 * 16 + l4];
    float bj4 = bias[4 * 16 + l4], bj5 = bias[5 * 16 + l4];
    float bj6 = bias[6 * 16 + l4], bj7 = bias[7 * 16 + l4];
    float p0 = 0.f, p1 = 0.f, p2 = 0.f, p3 = 0.f;
    float p4 = 0.f, p5 = 0.f, p6 = 0.f, p7 = 0.f;

    int gw = blockIdx.x * 4 + wv;
    int stride = gridDim.x * 4;

    for (int pr = gw; pr < NPAIR; pr += stride) {
        int v = pr * 2 + half;
        int beg = rp[v];
        int cnt = rp[v + 1] - beg;
        int co = __shfl_xor(cnt, 32);
        int cm = cnt > co ? cnt : co;

        int s0 = 0, s1 = 0, s2 = 0, s3 = 0, s4 = 0, s5 = 0, s6 = 0, s7 = 0;
        int tsl = 0;
        for (int wk = 0; wk < cm; wk += 32) {
            int widx = wk + il;
            int ai = beg + widx; ai = ai < NE ? ai : NE - 1;
            int ent = ad[ai];
            ent = (widx < cnt) ? ent : NN;
            int r = cm - wk;
            unsigned aacc = 0u, bacc = 0u;
            KS(0) KS(1) KS(2) KS(3)
            if (r > 8)  { KS(4) KS(5) KS(6) KS(7) }
            if (r > 16) { KS(8) KS(9) KS(10) KS(11) }
            if (r > 24) { KS(12) KS(13) KS(14) KS(15) }
            tsl += r > 24 ? 16 : r > 16 ? 12 : r > 8 ? 8 : 4;
            s0 += (int)(aacc & 0xFFu);         s1 += (int)(bacc & 0xFFu);
            s2 += (int)((aacc >> 8) & 0xFFu);  s3 += (int)((bacc >> 8) & 0xFFu);
            s4 += (int)((aacc >> 16) & 0xFFu); s5 += (int)((bacc >> 16) & 0xFFu);
            s6 += (int)(aacc >> 24);           s7 += (int)(bacc >> 24);
        }
        int b8 = tsl << 3;
        s0 -= b8; s1 -= b8; s2 -= b8; s3 -= b8;
        s4 -= b8; s5 -= b8; s6 -= b8; s7 -= b8;
        // fold edge-parity groups (e=0 + e=1)
        s0 += __shfl_xor(s0, 16); s1 += __shfl_xor(s1, 16);
        s2 += __shfl_xor(s2, 16); s3 += __shfl_xor(s3, 16);
        s4 += __shfl_xor(s4, 16); s5 += __shfl_xor(s5, 16);
        s6 += __shfl_xor(s6, 16); s7 += __shfl_xor(s7, 16);
        if (egrp == 0) {
            unsigned su = *reinterpret_cast<const unsigned*>(hpb + (((unsigned)v << 6) | ch4));
            float dv = rsqrtf((float)(cnt + 1)) * H4INV;
            p0 += fmaxf(dv * (float)(s0 + (int)(su & 0xFu) - 8) + bj0, 0.f);
            p1 += fmaxf(dv * (float)(s1 + (int)((su >> 4) & 0xFu) - 8) + bj1, 0.f);
            p2 += fmaxf(dv * (float)(s2 + (int)((su >> 8) & 0xFu) - 8) + bj2, 0.f);
            p3 += fmaxf(dv * (float)(s3 + (int)((su >> 12) & 0xFu) - 8) + bj3, 0.f);
            p4 += fmaxf(dv * (float)(s4 + (int)((su >> 16) & 0xFu) - 8) + bj4, 0.f);
            p5 += fmaxf(dv * (float)(s5 + (int)((su >> 20) & 0xFu) - 8) + bj5, 0.f);
            p6 += fmaxf(dv * (float)(s6 + (int)((su >> 24) & 0xFu) - 8) + bj6, 0.f);
            p7 += fmaxf(dv * (float)(s7 + (int)(su >> 28) - 8) + bj7, 0.f);
        }
    }
    // fold nodes (e=1 lanes hold zeros; xor32 combines half 0 e0 with half 1 e0)
    p0 += __shfl_xor(p0, 32); p1 += __shfl_xor(p1, 32);
    p2 += __shfl_xor(p2, 32); p3 += __shfl_xor(p3, 32);
    p4 += __shfl_xor(p4, 32); p5 += __shfl_xor(p5, 32);
    p6 += __shfl_xor(p6, 32); p7 += __shfl_xor(p7, 32);

    __shared__ float red[4][DD];
    if (lane < 16) {
        red[wv][0 * 16 + lane] = p0; red[wv][1 * 16 + lane] = p1;
        red[wv][2 * 16 + lane] = p2; red[wv][3 * 16 + lane] = p3;
        red[wv][4 * 16 + lane] = p4; red[wv][5 * 16 + lane] = p5;
        red[wv][6 * 16 + lane] = p6; red[wv][7 * 16 + lane] = p7;
    }
    __syncthreads();
    if (tid < DD)
        unsafeAtomicAdd(&go[tid], red[0][tid] + red[1][tid] + red[2][tid] + red[3][tid]);
}

// ---- head MLP: 256 threads, float4 weight reads, split-j reduction ----
__global__ __launch_bounds__(256) void k_head(const float* __restrict__ g,
    const float* __restrict__ w1, const float* __restrict__ b1,
    const float* __restrict__ w2, const float* __restrict__ b2,
    const float* __restrict__ w3, const float* __restrict__ b3,
    const float* __restrict__ f1w, const float* __restrict__ f1b,
    const float* __restrict__ f2w, const float* __restrict__ f2b,
    float* __restrict__ out) {
    __shared__ float xin[384], part[256], h1[128], h2[128], aw[3], xctx[128];
    int t = threadIdx.x;
    int o = t & 127, half = t >> 7;
    for (int i = t; i < 384; i += 256) xin[i] = g[i];
    __syncthreads();
    {
        const float4* wrow = reinterpret_cast<const float4*>(w1 + o * 384 + half * 192);
        const float* xi = xin + half * 192;
        float s = 0.f;
#pragma unroll
        for (int j4 = 0; j4 < 48; ++j4) {
            float4 w = wrow[j4];
            s += w.x * xi[j4 * 4] + w.y * xi[j4 * 4 + 1] + w.z * xi[j4 * 4 + 2] + w.w * xi[j4 * 4 + 3];
        }
        part[t] = s;
    }
    __syncthreads();
    if (t < 128) h1[t] = fmaxf(part[t] + part[t + 128] + b1[t], 0.f);
    __syncthreads();
    {
        const float4* wrow = reinterpret_cast<const float4*>(w2 + o * 128 + half * 64);
        const float* xi = h1 + half * 64;
        float s = 0.f;
#pragma unroll
        for (int j4 = 0; j4 < 16; ++j4) {
            float4 w = wrow[j4];
            s += w.x * xi[j4 * 4] + w.y * xi[j4 * 4 + 1] + w.z * xi[j4 * 4 + 2] + w.w * xi[j4 * 4 + 3];
        }
        part[t] = s;
    }
    __syncthreads();
    if (t < 128) h2[t] = fmaxf(part[t] + part[t + 128] + b2[t], 0.f);
    __syncthreads();
    if (t < 3) {
        float sl = b3[t];
        for (int j = 0; j < 128; ++j) sl += h2[j] * w3[t * 128 + j];
        aw[t] = sl;
    }
    __syncthreads();
    if (t == 0) {
        float mx = fmaxf(aw[0], fmaxf(aw[1], aw[2]));
        float e0 = expf(aw[0] - mx), e1 = expf(aw[1] - mx), e2 = expf(aw[2] - mx);
        float inv = 1.f / (e0 + e1 + e2);
        aw[0] = e0 * inv; aw[1] = e1 * inv; aw[2] = e2 * inv;
    }
    __syncthreads();
    if (t < 128) xctx[t] = aw[0] * xin[t] + aw[1] * xin[128 + t] + aw[2] * xin[256 + t];
    __syncthreads();
    {
        const float* fw = half ? f2w : f1w;
        const float* fb = half ? f2b : f1b;
        const float4* wrow = reinterpret_cast<const float4*>(fw + o * 128);
        float s = fb[o];
#pragma unroll
        for (int j4 = 0; j4 < 32; ++j4) {
            float4 w = wrow[j4];
            s += w.x * xctx[j4 * 4] + w.y * xctx[j4 * 4 + 1] + w.z * xctx[j4 * 4 + 2] + w.w * xctx[j4 * 4 + 3];
        }
        out[half * 128 + o] = tanhf(s);
    }
}

extern "C" void kernel_launch(void* const* d_in, const int* in_sizes, int n_in,
                              void* d_out, int out_size, void* d_ws, size_t ws_size,
                              hipStream_t stream) {
    (void)in_sizes; (void)n_in; (void)out_size; (void)ws_size;

    const float* x[3]  = {(const float*)d_in[0], (const float*)d_in[1], (const float*)d_in[2]};
    const int*   ei[3] = {(const int*)d_in[3], (const int*)d_in[4], (const int*)d_in[5]};
    const float* cw[3] = {(const float*)d_in[6], (const float*)d_in[8], (const float*)d_in[10]};
    const float* cb[3] = {(const float*)d_in[7], (const float*)d_in[9], (const float*)d_in[11]};

    // layout (binned overlaid by hp4: binned dead after k_sort3)
    char* ws = (char*)d_ws;
    int*            adj    = (int*)ws;                         //  9,600,000
    int*            deg    = (int*)(ws + 9600000);             //    600,000
    int*            rowptr = (int*)(ws + 10200000);            //    600,192
    int*            bHist  = (int*)(ws + 10800192);            //      9,408
    int*            bOff   = (int*)(ws + 10809600);            //      9,408
    int*            bCur   = (int*)(ws + 10819008);            //      9,408
    float*          g      = (float*)(ws + 10828416);          //      1,536
    unsigned short* wtg    = (unsigned short*)(ws + 10830080); //     98,304
    char*           uni    = ws + 10928384;                    // union region
    unsigned int*   binned = (unsigned int*)uni;               //  9,600,000
    unsigned char*  hp4    = (unsigned char*)uni;              //  9,600,192 (3 x (NN+1) x 64)

    dim3 bin_grid(BIN_BLOCKS, 3);
    k_wt3   <<<3, 256, 0, stream>>>(cw[0], cw[1], cw[2], wtg, bHist, g);
    k_bcnt3 <<<bin_grid, 256, 0, stream>>>(ei[0], ei[1], ei[2], bHist);
    k_bscan3<<<3, 64, 0, stream>>>(bHist, bOff, bCur);
    k_bin3  <<<bin_grid, 256, 0, stream>>>(ei[0], ei[1], ei[2], bCur, binned);
    k_sort3 <<<dim3(NB, 3), 256, 0, stream>>>(binned, bOff, adj, deg, rowptr);

    k_gemmb<<<dim3(NB, 3), 256, 0, stream>>>(x[0], x[1], x[2], wtg, deg, hp4, NN);
    k_gath4<<<dim3(2048, 3), 256, 0, stream>>>(hp4, rowptr, adj,
                                               cb[0], cb[1], cb[2], g);

    k_head<<<1, 256, 0, stream>>>(g,
        (const float*)d_in[12], (const float*)d_in[13],
        (const float*)d_in[14], (const float*)d_in[15],
        (const float*)d_in[16], (const float*)d_in[17],
        (const float*)d_in[18], (const float*)d_in[19],
        (const float*)d_in[20], (const float*)d_in[21],
        (float*)d_out);
}